// Round 6
// baseline (1144.892 us; speedup 1.0000x reference)
//
#include <hip/hip_runtime.h>
#include <hip/hip_bf16.h>
#include <math.h>

typedef unsigned short u16;
typedef __attribute__((ext_vector_type(4))) float f32x4;
typedef __attribute__((ext_vector_type(8))) short s16x8;

__device__ __forceinline__ float b2f(u16 u){
  union { unsigned u; float f; } v; v.u = ((unsigned)u) << 16; return v.f;
}
__device__ __forceinline__ u16 f2b(float f){
  union { float f; unsigned u; } v; v.f = f;
  unsigned r = v.u + 0x7fffu + ((v.u >> 16) & 1u);
  return (u16)(r >> 16);
}

// async global->LDS, 16B per lane; LDS dest = wave-uniform base + lane*16
__device__ __forceinline__ void gload_lds(const u16* g, u16* l){
  __builtin_amdgcn_global_load_lds(
      (const __attribute__((address_space(1))) unsigned*)g,
      (__attribute__((address_space(3))) unsigned*)l, 16, 0, 0);
}

// bijective chunked XCD swizzle (m204)
__device__ __forceinline__ int chunk_swz(int bid, int nwg){
  int q = nwg >> 3, r = nwg & 7;
  int xcd = bid & 7, off = bid >> 3;
  return (xcd < r ? xcd*(q+1) : r*(q+1) + (xcd-r)*q) + off;
}

__global__ void zero_k(int* __restrict__ p, int n){
  int i = blockIdx.x*256 + threadIdx.x;
  if(i < n) p[i] = 0;
}

// ---------- batched prep kernels ----------
struct T6 { const float* W[6]; u16* O[6]; int K[6]; };
__global__ void transpose6(T6 a){
  int r = blockIdx.y;
  int idx = blockIdx.x*256 + threadIdx.x;
  int K = a.K[r];
  if(idx < K*256){ int k = idx >> 8, n = idx & 255; a.O[r][n*K + k] = f2b(a.W[r][idx]); }
}

struct F6 { const float* Wk[6]; const float* A[6]; u16* O[6]; };
__global__ void foldw6(F6 fa){
  int r = blockIdx.y;
  int idx = blockIdx.x*256 + threadIdx.x;
  int n = idx >> 8, k = idx & 255;
  int h = n >> 5, f = n & 31;
  const float* Wk = fa.Wk[r]; const float* A = fa.A[r];
  float s = 0.f;
  #pragma unroll 8
  for(int d = 0; d < 32; d++)
    s += Wk[k*256 + h*32 + d] * A[h*1024 + d*32 + f];
  fa.O[r][n*256 + k] = f2b(s);
}

struct Fb6 { const float* bk[6]; const float* A[6]; float* O[6]; };
__global__ void foldb6(Fb6 fa){
  int r = blockIdx.x;
  int n = threadIdx.x;
  int h = n >> 5, f = n & 31;
  float s = 0.f;
  for(int d = 0; d < 32; d++)
    s += fa.bk[r][h*32 + d] * fa.A[r][h*1024 + d*32 + f];
  fa.O[r][n] = s;
}

// ---------- batched CSR build (3 relations) ----------
struct CSR3 {
  const int* src[3]; const int* dst[3]; int n[3];
  int* cnt[3]; int* rs[3]; int* cur[3]; int* col[3]; int* tot[3];
};
__global__ void count3(CSR3 c, int E){
  int r = blockIdx.y;
  int e = blockIdx.x*256 + threadIdx.x;
  if(e < E) atomicAdd(&c.cnt[r][c.dst[r][e]], 1);
}
__global__ void alloc3(CSR3 c){
  int r = blockIdx.y;
  int i = blockIdx.x*256 + threadIdx.x;
  if(i < c.n[r]) c.rs[r][i] = atomicAdd(c.tot[r], c.cnt[r][i]);
}
__global__ void fill3(CSR3 c, int E){
  int r = blockIdx.y;
  int e = blockIdx.x*256 + threadIdx.x;
  if(e < E){
    int d = c.dst[r][e];
    int p = c.rs[r][d] + atomicAdd(&c.cur[r][d], 1);
    c.col[r][p] = c.src[r][e];
  }
}

// ---------- proj GEMM (fp32 A, K=128): 2-desc batch, proven 2-barrier loop ----------
struct GMD {
  const void* A; const u16* BT; const float* bias; void* C;
  int M, K, lda, ldc, lgy, base, epi;
};
struct GM5 { GMD g[5]; int n, nblk; };

template<int AF>
__global__ __launch_bounds__(256) void gemm_multi(GM5 P){
  __shared__ u16 sh[2][128*64];
  const int t = threadIdx.x;
  const int l = chunk_swz(blockIdx.x, P.nblk);
  int g = 0;
  #pragma unroll
  for(int i = 1; i < 5; i++) if(i < P.n && l >= P.g[i].base) g = i;
  const GMD d = P.g[g];
  const int local = l - d.base;
  const int x = local >> d.lgy;
  const int y = local & ((1 << d.lgy) - 1);
  const int m0 = x << 7, n0 = y << 7;
  const int M = d.M, K = d.K, lda = d.lda, ldc = d.ldc;
  const int w = t >> 6, lane = t & 63;
  const int wm = (w >> 1) << 6;
  const int wn = (w & 1) << 6;
  const int lr = lane & 15, lq = lane >> 4;
  f32x4 acc[4][4];
  #pragma unroll
  for(int i=0;i<4;i++)
    #pragma unroll
    for(int j=0;j<4;j++) acc[i][j] = (f32x4){0.f,0.f,0.f,0.f};

  {
    u16* As = sh[0];
    u16* Bs = sh[0] + 128*32;
    const int jr = lane >> 2, sp = lane & 3;
    for(int k0 = 0; k0 < K; k0 += 32){
      const float* Af = (const float*)d.A;
      #pragma unroll
      for(int j = 0; j < 2; j++){
        int s = t + j*256;
        int rr = s >> 2, p2 = s & 3;
        int sl = p2 ^ (rr & 3);
        int gm = m0 + rr; if(gm > M-1) gm = M-1;
        const float* gp = Af + (size_t)gm*lda + k0 + sl*8;
        float4 f0 = *(const float4*)gp;
        float4 f1 = *(const float4*)(gp + 4);
        s16x8 v;
        v[0]=(short)f2b(f0.x); v[1]=(short)f2b(f0.y); v[2]=(short)f2b(f0.z); v[3]=(short)f2b(f0.w);
        v[4]=(short)f2b(f1.x); v[5]=(short)f2b(f1.y); v[6]=(short)f2b(f1.z); v[7]=(short)f2b(f1.w);
        *(s16x8*)&As[rr*32 + p2*8] = v;
      }
      #pragma unroll
      for(int i = 0; i < 2; i++){
        int rr = w*32 + i*16 + jr;
        int sl = sp ^ (rr & 3);
        gload_lds(d.BT + (size_t)(n0 + rr)*K + k0 + sl*8, &Bs[(w*32 + i*16)*32]);
      }
      __syncthreads();
      s16x8 a[4], b[4];
      #pragma unroll
      for(int mt=0; mt<4; mt++)
        a[mt] = *(const s16x8*)&As[(wm + mt*16 + lr)*32 + ((lq ^ (lr&3)) << 3)];
      #pragma unroll
      for(int nt=0; nt<4; nt++)
        b[nt] = *(const s16x8*)&Bs[(wn + nt*16 + lr)*32 + ((lq ^ (lr&3)) << 3)];
      #pragma unroll
      for(int mt=0; mt<4; mt++)
        #pragma unroll
        for(int nt=0; nt<4; nt++)
          acc[mt][nt] = __builtin_amdgcn_mfma_f32_16x16x32_bf16(a[mt], b[nt], acc[mt][nt], 0, 0, 0);
      __syncthreads();
    }
  }

  // bf16 out via LDS restage (proj outputs are always bf16)
  u16* shm = sh[0];
  u16* C = (u16*)d.C;
  #pragma unroll
  for(int p = 0; p < 2; p++){
    if((w & 1) == p){
      #pragma unroll
      for(int nt=0; nt<4; nt++){
        const int cp = nt*16 + lr;
        const float bc = d.bias[n0 + p*64 + cp];
        #pragma unroll
        for(int mt=0; mt<4; mt++)
          #pragma unroll
          for(int i=0;i<4;i++){
            int row = wm + mt*16 + lq*4 + i;
            int so = (cp >> 3) ^ (row & 7);
            shm[row*64 + so*8 + (cp & 7)] = f2b(acc[mt][nt][i] + bc);
          }
      }
    }
    __syncthreads();
    {
      int row = t >> 1, hh = t & 1;
      if(m0 + row < M){
        u16* dst = C + (size_t)(m0 + row)*ldc + n0 + p*64 + hh*32;
        #pragma unroll
        for(int j=0;j<4;j++){
          int so = (hh*4 + j) ^ (row & 7);
          *(s16x8*)(dst + j*8) = *(const s16x8*)&shm[row*64 + so*8];
        }
      }
    }
    __syncthreads();
  }
}

// ---------- mega GEMM: one block = 128 A-rows, A staged ONCE in LDS, ----------
// all N-panels sharing those rows computed in sequence; B read global->regs
// (L2-resident weights). Inner K-loop is barrier-free.
struct Panel { const u16* BT; const float* bias; void* C; int ldc, epi; };
struct Mega { const u16* A[2]; int M[2]; int np[2]; int pb[2]; int split; Panel p[16]; };

__global__ __launch_bounds__(256) void gemm_mega(Mega P){
  __shared__ u16 As[128*256];   // 64KB; 16B slots XOR-swizzled by (row&7)
  __shared__ u16 Cs[128*64];    // 16KB bf16 C restage
  const int t = threadIdx.x;
  const int blk = blockIdx.x;
  const int side = (blk >= P.split) ? 1 : 0;
  const u16* A = P.A[side];
  const int M = P.M[side];
  const int np = P.np[side];
  const int pb = P.pb[side];
  const int m0 = (side ? blk - P.split : blk) << 7;
  const int w = t >> 6, lane = t & 63;
  const int wm = (w >> 1) << 6;
  const int wn = (w & 1) << 6;
  const int lr = lane & 15, lq = lane >> 4;

  // ---- stage A[128x256] once: per issue 64 lanes x 16B = 2 rows ----
  #pragma unroll
  for(int i = 0; i < 16; i++){
    int rbase = w*32 + i*2;
    int rr = rbase + (lane >> 5);
    int sp = lane & 31;
    int sl = sp ^ (rr & 7);
    int gm = m0 + rr; if(gm > M-1) gm = M-1;
    gload_lds(A + (size_t)gm*256 + sl*8, &As[rbase*256]);
  }
  asm volatile("s_waitcnt vmcnt(0)" ::: "memory");
  __syncthreads();

  for(int p = 0; p < np; p++){
    const u16* Bp = P.p[pb + p].BT;
    const float* bias = P.p[pb + p].bias;
    void* Cp = P.p[pb + p].C;
    const int ldc = P.p[pb + p].ldc;
    const int epi = P.p[pb + p].epi;
    f32x4 acc[4][4];
    #pragma unroll
    for(int i=0;i<4;i++)
      #pragma unroll
      for(int j=0;j<4;j++) acc[i][j] = (f32x4){0.f,0.f,0.f,0.f};

    #pragma unroll 2
    for(int ts = 0; ts < 8; ts++){
      s16x8 b[4], a[4];
      #pragma unroll
      for(int nt=0;nt<4;nt++)
        b[nt] = *(const s16x8*)&Bp[(size_t)(wn + nt*16 + lr)*256 + ts*32 + lq*8];
      #pragma unroll
      for(int mt=0;mt<4;mt++){
        int ra = wm + mt*16 + lr;
        int ps = (ts*4 + lq) ^ (ra & 7);
        a[mt] = *(const s16x8*)&As[ra*256 + ps*8];
      }
      #pragma unroll
      for(int mt=0;mt<4;mt++)
        #pragma unroll
        for(int nt=0;nt<4;nt++)
          acc[mt][nt] = __builtin_amdgcn_mfma_f32_16x16x32_bf16(a[mt], b[nt], acc[mt][nt], 0, 0, 0);
    }

    if(epi == 1){
      float* C = (float*)Cp;
      #pragma unroll
      for(int nt=0; nt<4; nt++){
        const int col = wn + nt*16 + lr;
        const float bc = bias[col];
        #pragma unroll
        for(int mt=0; mt<4; mt++)
          #pragma unroll
          for(int i=0;i<4;i++){
            int row = m0 + wm + mt*16 + lq*4 + i;
            if(row < M) C[(size_t)row*ldc + col] = acc[mt][nt][i] + bc;
          }
      }
    } else {
      u16* C = (u16*)Cp;
      #pragma unroll
      for(int p2 = 0; p2 < 2; p2++){
        if((w & 1) == p2){
          #pragma unroll
          for(int nt=0; nt<4; nt++){
            const int cp = nt*16 + lr;
            const float bc = bias[p2*64 + cp];
            #pragma unroll
            for(int mt=0; mt<4; mt++)
              #pragma unroll
              for(int i=0;i<4;i++){
                int row = wm + mt*16 + lq*4 + i;
                int so = (cp >> 3) ^ (row & 7);
                Cs[row*64 + so*8 + (cp & 7)] = f2b(acc[mt][nt][i] + bc);
              }
          }
        }
        __syncthreads();
        {
          int row = t >> 1, hh = t & 1;
          if(m0 + row < M){
            u16* dst = C + (size_t)(m0 + row)*ldc + p2*64 + hh*32;
            #pragma unroll
            for(int j=0;j<4;j++){
              int so = (hh*4 + j) ^ (row & 7);
              *(s16x8*)(dst + j*8) = *(const s16x8*)&Cs[row*64 + so*8];
            }
          }
        }
        __syncthreads();
      }
    }
  }
}

// ---------- epilogue GEMM: A staged once, B global->regs, barrier-free K-loop ----------
struct GE { const u16* A; const u16* BT; const float* bias; float* C;
            const u16* X; const float* skip; const float* prelu; int M, base; };
struct GE2 { GE g[2]; int nblk; };

__global__ __launch_bounds__(256) void gemm_epi2(GE2 P){
  __shared__ u16 As[64*256];   // 32KB
  const int t = threadIdx.x;
  const int l = chunk_swz(blockIdx.x, P.nblk);
  const int g = (l >= P.g[1].base) ? 1 : 0;
  const GE d = P.g[g];
  const int m0 = (l - d.base) << 6;
  const int M = d.M;
  const int w = t >> 6, lane = t & 63;
  const int wn = w << 6;
  const int lr = lane & 15, lq = lane >> 4;

  #pragma unroll
  for(int i = 0; i < 8; i++){
    int rbase = w*16 + i*2;
    int rr = rbase + (lane >> 5);
    int sp = lane & 31;
    int sl = sp ^ (rr & 7);
    int gm = m0 + rr; if(gm > M-1) gm = M-1;
    gload_lds(d.A + (size_t)gm*512 + sl*8, &As[rbase*256]);
  }
  asm volatile("s_waitcnt vmcnt(0)" ::: "memory");
  __syncthreads();

  f32x4 acc[4][4];
  #pragma unroll
  for(int i=0;i<4;i++)
    #pragma unroll
    for(int j=0;j<4;j++) acc[i][j] = (f32x4){0.f,0.f,0.f,0.f};

  #pragma unroll 2
  for(int ts = 0; ts < 8; ts++){
    s16x8 a[4], b[4];
    #pragma unroll
    for(int nt=0;nt<4;nt++)
      b[nt] = *(const s16x8*)&d.BT[(size_t)(wn + nt*16 + lr)*256 + ts*32 + lq*8];
    #pragma unroll
    for(int mt=0;mt<4;mt++){
      int ra = mt*16 + lr;
      int ps = (ts*4 + lq) ^ (ra & 7);
      a[mt] = *(const s16x8*)&As[ra*256 + ps*8];
    }
    #pragma unroll
    for(int mt=0;mt<4;mt++)
      #pragma unroll
      for(int nt=0;nt<4;nt++)
        acc[mt][nt] = __builtin_amdgcn_mfma_f32_16x16x32_bf16(a[mt], b[nt], acc[mt][nt], 0, 0, 0);
  }

  const float beta = 1.f/(1.f + __expf(-d.skip[0]));
  #pragma unroll
  for(int nt=0; nt<4; nt++){
    const int col = wn + nt*16 + lr;
    const float bc = d.bias[col];
    const float pw = d.prelu[col];
    #pragma unroll
    for(int mt=0; mt<4; mt++){
      #pragma unroll
      for(int i=0;i<4;i++){
        int row = m0 + mt*16 + lq*4 + i;
        if(row < M){
          float v = acc[mt][nt][i] + bc;
          float xv = b2f(d.X[(size_t)row*256 + col]);
          v = beta*v + (1.f - beta)*xv;
          v = v > 0.f ? v : pw*v;
          d.C[(size_t)row*256 + col] = v;
        }
      }
    }
  }
}

// ---------- message pass + gelu ----------
template<int NREL>
__global__ __launch_bounds__(256) void message_gelu_k(
    const u16* __restrict__ KV1, const float* __restrict__ p1,
    const int* __restrict__ rs1, const int* __restrict__ cnt1, const int* __restrict__ col1,
    const u16* __restrict__ KV2, const float* __restrict__ p2,
    const int* __restrict__ rs2, const int* __restrict__ cnt2, const int* __restrict__ col2,
    float* __restrict__ Qio, int n_dst)
{
  int node = (blockIdx.x << 2) + (threadIdx.x >> 6);
  if(node >= n_dst) return;
  int lane = threadIdx.x & 63;
  float4 qv = *(const float4*)(Qio + (size_t)node*256 + (lane << 2));
  float q0=qv.x, q1=qv.y, q2=qv.z, q3=qv.w;
  float o0=0.f, o1=0.f, o2=0.f, o3=0.f;
  #pragma unroll
  for(int rel = 0; rel < NREL; rel++){
    const u16* KV = rel ? KV2 : KV1;
    const float* pr = rel ? p2 : p1;
    const int* rs = rel ? rs2 : rs1;
    const int* cn = rel ? cnt2 : cnt1;
    const int* cl = rel ? col2 : col1;
    float ps = pr[lane >> 3] * 0.17677669529663687f;   // p[h]/sqrt(32)
    float a0=0.f,a1=0.f,a2=0.f,a3=0.f,ss=0.f,mx=-1e30f;
    int r0 = rs[node], deg = cn[node];
    int i = 0;
    for(; i + 2 <= deg; i += 2){
      const u16* e0 = KV + (size_t)cl[r0+i]  *512 + (lane<<2);
      const u16* e1 = KV + (size_t)cl[r0+i+1]*512 + (lane<<2);
      ushort4 ka = *(const ushort4*)e0;
      ushort4 va = *(const ushort4*)(e0 + 256);
      ushort4 kb = *(const ushort4*)e1;
      ushort4 vb = *(const ushort4*)(e1 + 256);
      float da = q0*b2f(ka.x) + q1*b2f(ka.y) + q2*b2f(ka.z) + q3*b2f(ka.w);
      float db = q0*b2f(kb.x) + q1*b2f(kb.y) + q2*b2f(kb.z) + q3*b2f(kb.w);
      da += __shfl_xor(da, 1); da += __shfl_xor(da, 2); da += __shfl_xor(da, 4);
      db += __shfl_xor(db, 1); db += __shfl_xor(db, 2); db += __shfl_xor(db, 4);
      float la = da * ps, lb = db * ps;
      float nm = fmaxf(mx, fmaxf(la, lb));
      float c  = __expf(mx - nm);
      float wa = __expf(la - nm);
      float wb = __expf(lb - nm);
      mx = nm;
      ss = ss*c + wa + wb;
      a0 = a0*c + wa*b2f(va.x) + wb*b2f(vb.x);
      a1 = a1*c + wa*b2f(va.y) + wb*b2f(vb.y);
      a2 = a2*c + wa*b2f(va.z) + wb*b2f(vb.z);
      a3 = a3*c + wa*b2f(va.w) + wb*b2f(vb.w);
    }
    if(i < deg){
      const u16* e0 = KV + (size_t)cl[r0+i]*512 + (lane<<2);
      ushort4 ka = *(const ushort4*)e0;
      ushort4 va = *(const ushort4*)(e0 + 256);
      float da = q0*b2f(ka.x) + q1*b2f(ka.y) + q2*b2f(ka.z) + q3*b2f(ka.w);
      da += __shfl_xor(da, 1); da += __shfl_xor(da, 2); da += __shfl_xor(da, 4);
      float la = da * ps;
      float nm = fmaxf(mx, la);
      float c  = __expf(mx - nm);
      float wa = __expf(la - nm);
      mx = nm;
      ss = ss*c + wa;
      a0 = a0*c + wa*b2f(va.x);
      a1 = a1*c + wa*b2f(va.y);
      a2 = a2*c + wa*b2f(va.z);
      a3 = a3*c + wa*b2f(va.w);
    }
    float inv = 1.f/(ss + 1e-16f);
    o0 += a0*inv; o1 += a1*inv; o2 += a2*inv; o3 += a3*inv;
  }
  const float c = 0.70710678118654752f;
  float g0 = 0.5f*o0*(1.f + erff(o0*c));
  float g1 = 0.5f*o1*(1.f + erff(o1*c));
  float g2 = 0.5f*o2*(1.f + erff(o2*c));
  float g3 = 0.5f*o3*(1.f + erff(o3*c));
  ushort4 ov;
  ov.x = f2b(g0); ov.y = f2b(g1); ov.z = f2b(g2); ov.w = f2b(g3);
  *(ushort4*)((u16*)Qio + (size_t)node*512 + (lane << 2)) = ov;
}

extern "C" void kernel_launch(void* const* d_in, const int* in_sizes, int n_in,
                              void* d_out, int out_size, void* d_ws, size_t ws_size,
                              hipStream_t stream)
{
  (void)n_in; (void)out_size;
  #define IN_F32(i) ((const float*)d_in[i])
  #define IN_I32(i) ((const int*)d_in[i])
  const int NG = in_sizes[0] / 128;
  const int ND = in_sizes[1] / 128;
  const int E  = in_sizes[34];

  char* p = (char*)d_ws;
  auto carve = [&](size_t bytes) -> void* {
    void* q = (void*)p; p += (bytes + 255) & ~(size_t)255; return q;
  };
  u16* XG   = (u16*)carve((size_t)NG*256*2);
  u16* XD   = (u16*)carve((size_t)ND*256*2);
  u16* KVG  = (u16*)carve((size_t)NG*512*2);   // g2d K|V (and g2g fallback)
  u16* KVD  = (u16*)carve((size_t)ND*512*2);   // d2g K|V
  u16* WTinG = (u16*)carve(256*128*2);
  u16* WTinD = (u16*)carve(256*128*2);
  u16* WTqG  = (u16*)carve(256*256*2);
  u16* WTqD  = (u16*)carve(256*256*2);
  u16* WTaG  = (u16*)carve(256*256*2);
  u16* WTaD  = (u16*)carve(256*256*2);
  u16* KVW[3]; for(int i=0;i<3;i++) KVW[i] = (u16*)carve(512*256*2);
  float* FBV[3]; for(int i=0;i<3;i++) FBV[i] = (float*)carve(512*4);
  const int zn = 2*(ND + 2*NG) + 8;
  int* zone = (int*)carve((size_t)zn*4);
  int* cnt0 = zone;            // ND
  int* cnt1 = cnt0 + ND;       // NG
  int* cnt2 = cnt1 + NG;       // NG
  int* cur0 = cnt2 + NG;       // ND
  int* cur1 = cur0 + ND;       // NG
  int* cur2 = cur1 + NG;       // NG
  int* tot  = cur2 + NG;       // 8
  int* rs0 = (int*)carve((size_t)ND*4);
  int* rs1 = (int*)carve((size_t)NG*4);
  int* rs2 = (int*)carve((size_t)NG*4);
  int* col0 = (int*)carve((size_t)E*4);
  int* col1 = (int*)carve((size_t)E*4);
  int* col2 = (int*)carve((size_t)E*4);
  // separate g2g KV buffer (r5 confirmed ws fits; keep guarded fallback)
  u16* KVG2 = nullptr;
  {
    size_t used = (size_t)(p - (char*)d_ws);
    size_t need = (size_t)NG*512*2 + 4096;
    if(ws_size >= used + need) KVG2 = (u16*)carve((size_t)NG*512*2);
  }

  float* QGio = (float*)d_out;                     // fp32 [NG,256]
  float* QDio = (float*)d_out + (size_t)NG*256;    // fp32 [ND,256]

  // ---- prep (batched) ----
  {
    T6 a;
    const int wi[6] = {2,13,6,17,10,21};
    u16* wo[6] = {WTinG, WTinD, WTqG, WTqD, WTaG, WTaD};
    const int kk[6] = {128,128,256,256,256,256};
    for(int i=0;i<6;i++){ a.W[i]=IN_F32(wi[i]); a.O[i]=wo[i]; a.K[i]=kk[i]; }
    transpose6<<<dim3(256,6), 256, 0, stream>>>(a);
  }
  {
    F6 a; Fb6 b;
    const int wk[6] = {4,8,15,19,4,8};
    const int bk[6] = {5,9,16,20,5,9};
    const int am[6] = {24,25,27,28,30,31};
    for(int i=0;i<6;i++){
      a.Wk[i]=IN_F32(wk[i]); a.A[i]=IN_F32(am[i]);
      a.O[i] = KVW[i>>1] + (size_t)(i & 1)*256*256;     // K rows 0-255, V rows 256-511
      b.bk[i]=IN_F32(bk[i]); b.A[i]=IN_F32(am[i]);
      b.O[i] = FBV[i>>1] + (i & 1)*256;
    }
    foldw6<<<dim3(256,6), 256, 0, stream>>>(a);
    foldb6<<<6, 256, 0, stream>>>(b);
  }
  // ---- CSR (batched) ----
  CSR3 c;
  c.src[0]=IN_I32(34); c.dst[0]=IN_I32(35); c.n[0]=ND;
  c.src[1]=IN_I32(36); c.dst[1]=IN_I32(37); c.n[1]=NG;
  c.src[2]=IN_I32(38); c.dst[2]=IN_I32(39); c.n[2]=NG;
  c.cnt[0]=cnt0; c.cnt[1]=cnt1; c.cnt[2]=cnt2;
  c.cur[0]=cur0; c.cur[1]=cur1; c.cur[2]=cur2;
  c.rs[0]=rs0; c.rs[1]=rs1; c.rs[2]=rs2;
  c.col[0]=col0; c.col[1]=col1; c.col[2]=col2;
  c.tot[0]=tot; c.tot[1]=tot+1; c.tot[2]=tot+2;
  const int eb = (E + 255) / 256;
  const int nb = (NG + 255) / 256;
  zero_k<<<(zn + 255) / 256, 256, 0, stream>>>(zone, zn);
  count3<<<dim3(eb,3), 256, 0, stream>>>(c, E);
  alloc3<<<dim3(nb,3), 256, 0, stream>>>(c);
  fill3<<<dim3(eb,3), 256, 0, stream>>>(c, E);

  const int xg = (NG + 127)/128, xd = (ND + 127)/128;

  // ---- input projections (batched: XG + XD) ----
  {
    GM5 pj{};
    pj.g[0].A = d_in[0]; pj.g[0].BT = WTinG; pj.g[0].bias = IN_F32(3);  pj.g[0].C = XG;
    pj.g[0].M = NG; pj.g[0].K = 128; pj.g[0].lda = 128; pj.g[0].ldc = 256;
    pj.g[0].lgy = 1; pj.g[0].base = 0; pj.g[0].epi = 0;
    pj.g[1].A = d_in[1]; pj.g[1].BT = WTinD; pj.g[1].bias = IN_F32(14); pj.g[1].C = XD;
    pj.g[1].M = ND; pj.g[1].K = 128; pj.g[1].lda = 128; pj.g[1].ldc = 256;
    pj.g[1].lgy = 1; pj.g[1].base = xg*2; pj.g[1].epi = 0;
    pj.n = 2; pj.nblk = xg*2 + xd*2;
    gemm_multi<1><<<pj.nblk, 256, 0, stream>>>(pj);
  }

  // ---- mid GEMMs: ONE mega dispatch (A staged once per 128-row panel) ----
  auto setPanel = [&](Panel& pn, const u16* BT, const float* bias, void* C,
                      int n0, int ldc, int epi, int elemSize){
    pn.BT = BT + (size_t)n0*256;
    pn.bias = bias + n0;
    pn.C = (char*)C + (size_t)n0*elemSize;
    pn.ldc = ldc; pn.epi = epi;
  };
  {
    Mega mg{};
    mg.A[0] = XG; mg.M[0] = NG; mg.pb[0] = 0;
    mg.A[1] = XD; mg.M[1] = ND; mg.pb[1] = 10;
    mg.split = xg;
    int gp = 0;
    for(int n0 = 0; n0 < 512; n0 += 128)   // KV_g2d -> KVG
      setPanel(mg.p[gp++], KVW[0], FBV[0], KVG, n0, 512, 0, 2);
    for(int n0 = 0; n0 < 256; n0 += 128)   // QG -> QGio (fp32)
      setPanel(mg.p[gp++], WTqG, IN_F32(7), QGio, n0, 256, 1, 4);
    if(KVG2)
      for(int n0 = 0; n0 < 512; n0 += 128) // KV_g2g -> KVG2
        setPanel(mg.p[gp++], KVW[2], FBV[2], KVG2, n0, 512, 0, 2);
    mg.np[0] = gp;
    int dp = 10;
    for(int n0 = 0; n0 < 256; n0 += 128)   // QD -> QDio (fp32)
      setPanel(mg.p[dp++], WTqD, IN_F32(18), QDio, n0, 256, 1, 4);
    for(int n0 = 0; n0 < 512; n0 += 128)   // KV_d2g -> KVD
      setPanel(mg.p[dp++], KVW[1], FBV[1], KVD, n0, 512, 0, 2);
    mg.np[1] = dp - 10;
    gemm_mega<<<xg + xd, 256, 0, stream>>>(mg);
  }

  // relation g2d message (needs QD + KV_g2d)
  message_gelu_k<1><<<(ND + 3) / 4, 256, 0, stream>>>(
      KVG, IN_F32(26), rs0, cnt0, col0,
      nullptr, nullptr, nullptr, nullptr, nullptr,
      QDio, ND);

  // fallback: no KVG2 -> compute KV_g2g into KVG after msg1 consumed it
  if(!KVG2){
    Mega mg{};
    mg.A[0] = XG; mg.M[0] = NG; mg.pb[0] = 0;
    mg.A[1] = XG; mg.M[1] = NG; mg.pb[1] = 10;   // unused side
    mg.split = xg;
    int gp = 0;
    for(int n0 = 0; n0 < 512; n0 += 128)
      setPanel(mg.p[gp++], KVW[2], FBV[2], KVG, n0, 512, 0, 2);
    mg.np[0] = gp; mg.np[1] = 0;
    gemm_mega<<<xg, 256, 0, stream>>>(mg);
  }

  // relations d2g + g2g message (dst=g)
  message_gelu_k<2><<<(NG + 3) / 4, 256, 0, stream>>>(
      KVD, IN_F32(29), rs1, cnt1, col1,
      KVG2 ? KVG2 : KVG, IN_F32(32), rs2, cnt2, col2,
      QGio, NG);

  // ---- final epilogue GEMMs (batched, in place over d_out) ----
  {
    GE2 ep{};
    ep.g[0].A = (const u16*)QGio; ep.g[0].BT = WTaG; ep.g[0].bias = IN_F32(11);
    ep.g[0].C = QGio; ep.g[0].X = XG; ep.g[0].skip = IN_F32(12); ep.g[0].prelu = IN_F32(33);
    ep.g[0].M = NG; ep.g[0].base = 0;
    ep.g[1].A = (const u16*)QDio; ep.g[1].BT = WTaD; ep.g[1].bias = IN_F32(22);
    ep.g[1].C = QDio; ep.g[1].X = XD; ep.g[1].skip = IN_F32(23); ep.g[1].prelu = IN_F32(33);
    ep.g[1].M = ND; ep.g[1].base = (NG + 63)/64;
    ep.nblk = (NG + 63)/64 + (ND + 63)/64;
    gemm_epi2<<<ep.nblk, 256, 0, stream>>>(ep);
  }
  #undef IN_F32
  #undef IN_I32
}

// Round 8
// 987.355 us; speedup vs baseline: 1.1596x; 1.1596x over previous
//
#include <hip/hip_runtime.h>
#include <hip/hip_bf16.h>
#include <math.h>

typedef unsigned short u16;
typedef __attribute__((ext_vector_type(4))) float f32x4;
typedef __attribute__((ext_vector_type(8))) short s16x8;

__device__ __forceinline__ float b2f(u16 u){
  union { unsigned u; float f; } v; v.u = ((unsigned)u) << 16; return v.f;
}
__device__ __forceinline__ u16 f2b(float f){
  union { float f; unsigned u; } v; v.f = f;
  unsigned r = v.u + 0x7fffu + ((v.u >> 16) & 1u);
  return (u16)(r >> 16);
}

// async global->LDS, 16B per lane; LDS dest = wave-uniform base + lane*16
__device__ __forceinline__ void gload_lds(const u16* g, u16* l){
  __builtin_amdgcn_global_load_lds(
      (const __attribute__((address_space(1))) unsigned*)g,
      (__attribute__((address_space(3))) unsigned*)l, 16, 0, 0);
}

// bijective chunked XCD swizzle (m204)
__device__ __forceinline__ int chunk_swz(int bid, int nwg){
  int q = nwg >> 3, r = nwg & 7;
  int xcd = bid & 7, off = bid >> 3;
  return (xcd < r ? xcd*(q+1) : r*(q+1) + (xcd-r)*q) + off;
}

__global__ void zero_k(int* __restrict__ p, int n){
  int i = blockIdx.x*256 + threadIdx.x;
  if(i < n) p[i] = 0;
}

// ---------- batched prep kernels ----------
struct T6 { const float* W[6]; u16* O[6]; int K[6]; };
__global__ void transpose6(T6 a){
  int r = blockIdx.y;
  int idx = blockIdx.x*256 + threadIdx.x;
  int K = a.K[r];
  if(idx < K*256){ int k = idx >> 8, n = idx & 255; a.O[r][n*K + k] = f2b(a.W[r][idx]); }
}

struct F6 { const float* Wk[6]; const float* A[6]; u16* O[6]; };
__global__ void foldw6(F6 fa){
  int r = blockIdx.y;
  int idx = blockIdx.x*256 + threadIdx.x;
  int n = idx >> 8, k = idx & 255;
  int h = n >> 5, f = n & 31;
  const float* Wk = fa.Wk[r]; const float* A = fa.A[r];
  float s = 0.f;
  #pragma unroll 8
  for(int d = 0; d < 32; d++)
    s += Wk[k*256 + h*32 + d] * A[h*1024 + d*32 + f];
  fa.O[r][n*256 + k] = f2b(s);
}

struct Fb6 { const float* bk[6]; const float* A[6]; float* O[6]; };
__global__ void foldb6(Fb6 fa){
  int r = blockIdx.x;
  int n = threadIdx.x;
  int h = n >> 5, f = n & 31;
  float s = 0.f;
  for(int d = 0; d < 32; d++)
    s += fa.bk[r][h*32 + d] * fa.A[r][h*1024 + d*32 + f];
  fa.O[r][n] = s;
}

// ---------- batched CSR build (3 relations) ----------
struct CSR3 {
  const int* src[3]; const int* dst[3]; int n[3];
  int* cnt[3]; int* rs[3]; int* cur[3]; int* col[3]; int* tot[3];
};
__global__ void count3(CSR3 c, int E){
  int r = blockIdx.y;
  int e = blockIdx.x*256 + threadIdx.x;
  if(e < E) atomicAdd(&c.cnt[r][c.dst[r][e]], 1);
}
__global__ void alloc3(CSR3 c){
  int r = blockIdx.y;
  int i = blockIdx.x*256 + threadIdx.x;
  if(i < c.n[r]) c.rs[r][i] = atomicAdd(c.tot[r], c.cnt[r][i]);
}
__global__ void fill3(CSR3 c, int E){
  int r = blockIdx.y;
  int e = blockIdx.x*256 + threadIdx.x;
  if(e < E){
    int d = c.dst[r][e];
    int p = c.rs[r][d] + atomicAdd(&c.cur[r][d], 1);
    c.col[r][p] = c.src[r][e];
  }
}

// ---------- descriptor-batched 64x128 GEMM ----------
// C[M, 128*2^lgy] = A[M,K] @ B + bias ; BT[N,K] bf16. BM=64 (occupancy tile:
// acc[2][4]=32 regs, LDS dbuf 24KB -> ~4-5 blocks/CU vs 2 at 128-tile).
// AF 1: A fp32 (converted during staging, 2-barrier loop; proj only).
// AF 0: T4-counted 2-phase pipeline, 3 gload_lds/stage -> vmcnt(3).
// epi 0: C bf16 via LDS-restaged 32B/thread stores. epi 1: C fp32 direct.
struct GMD {
  const void* A; const u16* BT; const float* bias; void* C;
  int M, K, lda, ldc, lgy, base, epi;
};
struct GM5 { GMD g[5]; int n, nblk; };

template<int AF>
__global__ __launch_bounds__(256) void gemm_multi(GM5 P){
  __shared__ u16 sh[2][96*64];   // per buffer: As[64x32] (2048) | Bs[128x32] (4096) u16
  const int t = threadIdx.x;
  const int l = chunk_swz(blockIdx.x, P.nblk);
  int g = 0;
  #pragma unroll
  for(int i = 1; i < 5; i++) if(i < P.n && l >= P.g[i].base) g = i;
  const GMD d = P.g[g];
  const int local = l - d.base;
  const int x = local >> d.lgy;
  const int y = local & ((1 << d.lgy) - 1);
  const int m0 = x << 6, n0 = y << 7;
  const int M = d.M, K = d.K, lda = d.lda, ldc = d.ldc;
  const int w = t >> 6, lane = t & 63;
  const int wm = (w >> 1) << 5;        // 0 / 32
  const int wn = (w & 1) << 6;         // 0 / 64
  const int lr = lane & 15, lq = lane >> 4;
  const int jr = lane >> 2;            // staging: row-in-16
  const int sp = lane & 3;             // staging: physical 16B slot
  f32x4 acc[2][4];
  #pragma unroll
  for(int i=0;i<2;i++)
    #pragma unroll
    for(int j=0;j<4;j++) acc[i][j] = (f32x4){0.f,0.f,0.f,0.f};

  if(AF){
    // ---- proj GEMMs: fp32 A converted in regs, simple 2-barrier loop ----
    u16* As = sh[0];
    u16* Bs = sh[0] + 64*32;
    for(int k0 = 0; k0 < K; k0 += 32){
      const float* Af = (const float*)d.A;
      {
        int rr = t >> 2, p2 = t & 3;     // 256 threads = 64 rows x 4 slots
        int sl = p2 ^ (rr & 3);
        int gm = m0 + rr; if(gm > M-1) gm = M-1;
        const float* gp = Af + (size_t)gm*lda + k0 + sl*8;
        float4 f0 = *(const float4*)gp;
        float4 f1 = *(const float4*)(gp + 4);
        s16x8 v;
        v[0]=(short)f2b(f0.x); v[1]=(short)f2b(f0.y); v[2]=(short)f2b(f0.z); v[3]=(short)f2b(f0.w);
        v[4]=(short)f2b(f1.x); v[5]=(short)f2b(f1.y); v[6]=(short)f2b(f1.z); v[7]=(short)f2b(f1.w);
        *(s16x8*)&As[rr*32 + p2*8] = v;
      }
      #pragma unroll
      for(int i = 0; i < 2; i++){
        int rr = w*32 + i*16 + jr;
        int sl = sp ^ (rr & 3);
        gload_lds(d.BT + (size_t)(n0 + rr)*K + k0 + sl*8, &Bs[(w*32 + i*16)*32]);
      }
      __syncthreads();
      s16x8 a[2], b[4];
      #pragma unroll
      for(int mt=0; mt<2; mt++)
        a[mt] = *(const s16x8*)&As[(wm + mt*16 + lr)*32 + ((lq ^ (lr&3)) << 3)];
      #pragma unroll
      for(int nt=0; nt<4; nt++)
        b[nt] = *(const s16x8*)&Bs[(wn + nt*16 + lr)*32 + ((lq ^ (lr&3)) << 3)];
      #pragma unroll
      for(int mt=0; mt<2; mt++)
        #pragma unroll
        for(int nt=0; nt<4; nt++)
          acc[mt][nt] = __builtin_amdgcn_mfma_f32_16x16x32_bf16(a[mt], b[nt], acc[mt][nt], 0, 0, 0);
      __syncthreads();
    }
  } else {
    // ---- T4-counted double-buffered pipeline (3 loads/wave/stage) ----
    const u16* Ab = (const u16*)d.A;
    auto stage = [&](int kk, int bi){
      u16* As = sh[bi];
      u16* Bs = sh[bi] + 64*32;
      {
        int rr = w*16 + jr;
        int sl = sp ^ (rr & 3);
        int gm = m0 + rr; if(gm > M-1) gm = M-1;
        gload_lds(Ab + (size_t)gm*lda + kk + sl*8, &As[(w*16)*32]);
      }
      #pragma unroll
      for(int i = 0; i < 2; i++){
        int rr = w*32 + i*16 + jr;
        int sl = sp ^ (rr & 3);
        gload_lds(d.BT + (size_t)(n0 + rr)*K + kk + sl*8, &Bs[(w*32 + i*16)*32]);
      }
    };
    const int ntile = K >> 5;
    int cur = 0;
    stage(0, 0);
    for(int ts = 0; ts < ntile; ++ts){
      if(ts + 1 < ntile){
        stage((ts+1) << 5, cur ^ 1);
        asm volatile("s_waitcnt vmcnt(3)" ::: "memory");   // stage(ts) done; (ts+1) in flight
      } else {
        asm volatile("s_waitcnt vmcnt(0)" ::: "memory");
      }
      __builtin_amdgcn_s_barrier();
      __builtin_amdgcn_sched_barrier(0);
      const u16* As = sh[cur];
      const u16* Bs = sh[cur] + 64*32;
      s16x8 a[2], b[4];
      #pragma unroll
      for(int mt=0; mt<2; mt++)
        a[mt] = *(const s16x8*)&As[(wm + mt*16 + lr)*32 + ((lq ^ (lr&3)) << 3)];
      #pragma unroll
      for(int nn=0; nn<4; nn++)
        b[nn] = *(const s16x8*)&Bs[(wn + nn*16 + lr)*32 + ((lq ^ (lr&3)) << 3)];
      asm volatile("s_waitcnt lgkmcnt(0)" ::: "memory");
      __builtin_amdgcn_sched_barrier(0);
      __builtin_amdgcn_s_setprio(1);
      #pragma unroll
      for(int mt=0; mt<2; mt++)
        #pragma unroll
        for(int nn=0; nn<4; nn++)
          acc[mt][nn] = __builtin_amdgcn_mfma_f32_16x16x32_bf16(a[mt], b[nn], acc[mt][nn], 0, 0, 0);
      __builtin_amdgcn_s_setprio(0);
      __builtin_amdgcn_s_barrier();      // all reads of buf cur done -> safe to overwrite
      __builtin_amdgcn_sched_barrier(0);
      cur ^= 1;
    }
  }

  if(d.epi == 1){
    float* C = (float*)d.C;
    #pragma unroll
    for(int nt=0; nt<4; nt++){
      const int col = n0 + wn + nt*16 + lr;
      const float bc = d.bias[col];
      #pragma unroll
      for(int mt=0; mt<2; mt++)
        #pragma unroll
        for(int i=0;i<4;i++){
          int row = m0 + wm + mt*16 + lq*4 + i;
          if(row < M) C[(size_t)row*ldc + col] = acc[mt][nt][i] + bc;
        }
    }
  } else {
    // bf16 out: restage through LDS (two 64-col passes), 32B/thread stores.
    // LDS tile [64 rows][64 u16], 16B slots XOR-swizzled by (row&7).
    u16* shm = sh[0];
    u16* C = (u16*)d.C;
    #pragma unroll
    for(int p = 0; p < 2; p++){
      if((w & 1) == p){
        #pragma unroll
        for(int nt=0; nt<4; nt++){
          const int cp = nt*16 + lr;                 // col within pass
          const float bc = d.bias[n0 + p*64 + cp];
          #pragma unroll
          for(int mt=0; mt<2; mt++)
            #pragma unroll
            for(int i=0;i<4;i++){
              int row = wm + mt*16 + lq*4 + i;
              int so = (cp >> 3) ^ (row & 7);
              shm[row*64 + so*8 + (cp & 7)] = f2b(acc[mt][nt][i] + bc);
            }
        }
      }
      __syncthreads();
      {
        int row = t >> 2, hh = t & 3;
        if(m0 + row < M){
          u16* dst = C + (size_t)(m0 + row)*ldc + n0 + p*64 + hh*16;
          #pragma unroll
          for(int j=0;j<2;j++){
            int so = (hh*2 + j) ^ (row & 7);
            *(s16x8*)(dst + j*8) = *(const s16x8*)&shm[row*64 + so*8];
          }
        }
      }
      __syncthreads();
    }
  }
}

// ---------- batched in-place epilogue GEMM (64x256 blocks own full rows) ----------
// A = bf16 rows embedded in d_out (u16 stride 512); v=acc+ba; v=beta*v+(1-beta)*X;
// PReLU; fp32 out in place. T4-counted pipeline (5 loads/stage -> vmcnt(5)).
struct GE { const u16* A; const u16* BT; const float* bias; float* C;
            const u16* X; const float* skip; const float* prelu; int M, base; };
struct GE2 { GE g[2]; int nblk; };

__global__ __launch_bounds__(256) void gemm_epi2(GE2 P){
  __shared__ u16 Abuf[2][64*32];
  __shared__ u16 Bbuf[2][256*32];
  const int t = threadIdx.x;
  const int l = chunk_swz(blockIdx.x, P.nblk);
  const int g = (l >= P.g[1].base) ? 1 : 0;
  const GE d = P.g[g];
  const int m0 = (l - d.base) << 6;
  const int M = d.M;
  const int w = t >> 6, lane = t & 63;
  const int wn = w << 6;
  const int lr = lane & 15, lq = lane >> 4;
  const int jr = lane >> 2, sp = lane & 3;
  f32x4 acc[4][4];
  #pragma unroll
  for(int i=0;i<4;i++)
    #pragma unroll
    for(int j=0;j<4;j++) acc[i][j] = (f32x4){0.f,0.f,0.f,0.f};

  auto stage = [&](int kk, int bi){
    {
      int rr = w*16 + jr;
      int sl = sp ^ (rr & 3);
      int gm = m0 + rr; if(gm > M-1) gm = M-1;
      gload_lds(d.A + (size_t)gm*512 + kk + sl*8, &Abuf[bi][(w*16)*32]);
    }
    #pragma unroll
    for(int i = 0; i < 4; i++){
      int rr = w*64 + i*16 + jr;
      int sl = sp ^ (rr & 3);
      gload_lds(d.BT + (size_t)rr*256 + kk + sl*8, &Bbuf[bi][(w*64 + i*16)*32]);
    }
  };
  int cur = 0;
  stage(0, 0);
  for(int ts = 0; ts < 8; ++ts){
    if(ts + 1 < 8){
      stage((ts+1) << 5, cur ^ 1);
      asm volatile("s_waitcnt vmcnt(5)" ::: "memory");
    } else {
      asm volatile("s_waitcnt vmcnt(0)" ::: "memory");
    }
    __builtin_amdgcn_s_barrier();
    __builtin_amdgcn_sched_barrier(0);
    const u16* As = Abuf[cur];
    const u16* Bs = Bbuf[cur];
    s16x8 a[4], b[4];
    #pragma unroll
    for(int mt=0; mt<4; mt++)
      a[mt] = *(const s16x8*)&As[(mt*16 + lr)*32 + ((lq ^ (lr&3)) << 3)];
    #pragma unroll
    for(int nn=0; nn<4; nn++)
      b[nn] = *(const s16x8*)&Bs[(wn + nn*16 + lr)*32 + ((lq ^ (lr&3)) << 3)];
    asm volatile("s_waitcnt lgkmcnt(0)" ::: "memory");
    __builtin_amdgcn_sched_barrier(0);
    __builtin_amdgcn_s_setprio(1);
    #pragma unroll
    for(int mt=0; mt<4; mt++)
      #pragma unroll
      for(int nn=0; nn<4; nn++)
        acc[mt][nn] = __builtin_amdgcn_mfma_f32_16x16x32_bf16(a[mt], b[nn], acc[mt][nn], 0, 0, 0);
    __builtin_amdgcn_s_setprio(0);
    __builtin_amdgcn_s_barrier();
    __builtin_amdgcn_sched_barrier(0);
    cur ^= 1;
  }

  const float beta = 1.f/(1.f + __expf(-d.skip[0]));
  #pragma unroll
  for(int nt=0; nt<4; nt++){
    const int col = wn + nt*16 + lr;
    const float bc = d.bias[col];
    const float pw = d.prelu[col];
    #pragma unroll
    for(int mt=0; mt<4; mt++){
      #pragma unroll
      for(int i=0;i<4;i++){
        int row = m0 + mt*16 + lq*4 + i;
        if(row < M){
          float v = acc[mt][nt][i] + bc;
          float xv = b2f(d.X[(size_t)row*256 + col]);
          v = beta*v + (1.f - beta)*xv;
          v = v > 0.f ? v : pw*v;
          d.C[(size_t)row*256 + col] = v;
        }
      }
    }
  }
}

// ---------- message pass + gelu ----------
template<int NREL>
__global__ __launch_bounds__(256) void message_gelu_k(
    const u16* __restrict__ KV1, const float* __restrict__ p1,
    const int* __restrict__ rs1, const int* __restrict__ cnt1, const int* __restrict__ col1,
    const u16* __restrict__ KV2, const float* __restrict__ p2,
    const int* __restrict__ rs2, const int* __restrict__ cnt2, const int* __restrict__ col2,
    float* __restrict__ Qio, int n_dst)
{
  int node = (blockIdx.x << 2) + (threadIdx.x >> 6);
  if(node >= n_dst) return;
  int lane = threadIdx.x & 63;
  float4 qv = *(const float4*)(Qio + (size_t)node*256 + (lane << 2));
  float q0=qv.x, q1=qv.y, q2=qv.z, q3=qv.w;
  float o0=0.f, o1=0.f, o2=0.f, o3=0.f;
  #pragma unroll
  for(int rel = 0; rel < NREL; rel++){
    const u16* KV = rel ? KV2 : KV1;
    const float* pr = rel ? p2 : p1;
    const int* rs = rel ? rs2 : rs1;
    const int* cn = rel ? cnt2 : cnt1;
    const int* cl = rel ? col2 : col1;
    float ps = pr[lane >> 3] * 0.17677669529663687f;   // p[h]/sqrt(32)
    float a0=0.f,a1=0.f,a2=0.f,a3=0.f,ss=0.f,mx=-1e30f;
    int r0 = rs[node], deg = cn[node];
    int i = 0;
    for(; i + 2 <= deg; i += 2){
      const u16* e0 = KV + (size_t)cl[r0+i]  *512 + (lane<<2);
      const u16* e1 = KV + (size_t)cl[r0+i+1]*512 + (lane<<2);
      ushort4 ka = *(const ushort4*)e0;
      ushort4 va = *(const ushort4*)(e0 + 256);
      ushort4 kb = *(const ushort4*)e1;
      ushort4 vb = *(const ushort4*)(e1 + 256);
      float da = q0*b2f(ka.x) + q1*b2f(ka.y) + q2*b2f(ka.z) + q3*b2f(ka.w);
      float db = q0*b2f(kb.x) + q1*b2f(kb.y) + q2*b2f(kb.z) + q3*b2f(kb.w);
      da += __shfl_xor(da, 1); da += __shfl_xor(da, 2); da += __shfl_xor(da, 4);
      db += __shfl_xor(db, 1); db += __shfl_xor(db, 2); db += __shfl_xor(db, 4);
      float la = da * ps, lb = db * ps;
      float nm = fmaxf(mx, fmaxf(la, lb));
      float c  = __expf(mx - nm);
      float wa = __expf(la - nm);
      float wb = __expf(lb - nm);
      mx = nm;
      ss = ss*c + wa + wb;
      a0 = a0*c + wa*b2f(va.x) + wb*b2f(vb.x);
      a1 = a1*c + wa*b2f(va.y) + wb*b2f(vb.y);
      a2 = a2*c + wa*b2f(va.z) + wb*b2f(vb.z);
      a3 = a3*c + wa*b2f(va.w) + wb*b2f(vb.w);
    }
    if(i < deg){
      const u16* e0 = KV + (size_t)cl[r0+i]*512 + (lane<<2);
      ushort4 ka = *(const ushort4*)e0;
      ushort4 va = *(const ushort4*)(e0 + 256);
      float da = q0*b2f(ka.x) + q1*b2f(ka.y) + q2*b2f(ka.z) + q3*b2f(ka.w);
      da += __shfl_xor(da, 1); da += __shfl_xor(da, 2); da += __shfl_xor(da, 4);
      float la = da * ps;
      float nm = fmaxf(mx, la);
      float c  = __expf(mx - nm);
      float wa = __expf(la - nm);
      mx = nm;
      ss = ss*c + wa;
      a0 = a0*c + wa*b2f(va.x);
      a1 = a1*c + wa*b2f(va.y);
      a2 = a2*c + wa*b2f(va.z);
      a3 = a3*c + wa*b2f(va.w);
    }
    float inv = 1.f/(ss + 1e-16f);
    o0 += a0*inv; o1 += a1*inv; o2 += a2*inv; o3 += a3*inv;
  }
  const float c = 0.70710678118654752f;
  float g0 = 0.5f*o0*(1.f + erff(o0*c));
  float g1 = 0.5f*o1*(1.f + erff(o1*c));
  float g2 = 0.5f*o2*(1.f + erff(o2*c));
  float g3 = 0.5f*o3*(1.f + erff(o3*c));
  ushort4 ov;
  ov.x = f2b(g0); ov.y = f2b(g1); ov.z = f2b(g2); ov.w = f2b(g3);
  *(ushort4*)((u16*)Qio + (size_t)node*512 + (lane << 2)) = ov;
}

extern "C" void kernel_launch(void* const* d_in, const int* in_sizes, int n_in,
                              void* d_out, int out_size, void* d_ws, size_t ws_size,
                              hipStream_t stream)
{
  (void)n_in; (void)out_size;
  #define IN_F32(i) ((const float*)d_in[i])
  #define IN_I32(i) ((const int*)d_in[i])
  const int NG = in_sizes[0] / 128;
  const int ND = in_sizes[1] / 128;
  const int E  = in_sizes[34];

  char* p = (char*)d_ws;
  auto carve = [&](size_t bytes) -> void* {
    void* q = (void*)p; p += (bytes + 255) & ~(size_t)255; return q;
  };
  u16* XG   = (u16*)carve((size_t)NG*256*2);
  u16* XD   = (u16*)carve((size_t)ND*256*2);
  u16* KVG  = (u16*)carve((size_t)NG*512*2);   // g2d K|V (and g2g fallback)
  u16* KVD  = (u16*)carve((size_t)ND*512*2);   // d2g K|V
  u16* WTinG = (u16*)carve(256*128*2);
  u16* WTinD = (u16*)carve(256*128*2);
  u16* WTqG  = (u16*)carve(256*256*2);
  u16* WTqD  = (u16*)carve(256*256*2);
  u16* WTaG  = (u16*)carve(256*256*2);
  u16* WTaD  = (u16*)carve(256*256*2);
  u16* KVW[3]; for(int i=0;i<3;i++) KVW[i] = (u16*)carve(512*256*2);
  float* FBV[3]; for(int i=0;i<3;i++) FBV[i] = (float*)carve(512*4);
  const int zn = 2*(ND + 2*NG) + 8;
  int* zone = (int*)carve((size_t)zn*4);
  int* cnt0 = zone;            // ND
  int* cnt1 = cnt0 + ND;       // NG
  int* cnt2 = cnt1 + NG;       // NG
  int* cur0 = cnt2 + NG;       // ND
  int* cur1 = cur0 + ND;       // NG
  int* cur2 = cur1 + NG;       // NG
  int* tot  = cur2 + NG;       // 8
  int* rs0 = (int*)carve((size_t)ND*4);
  int* rs1 = (int*)carve((size_t)NG*4);
  int* rs2 = (int*)carve((size_t)NG*4);
  int* col0 = (int*)carve((size_t)E*4);
  int* col1 = (int*)carve((size_t)E*4);
  int* col2 = (int*)carve((size_t)E*4);
  // separate g2g KV buffer (breaks WAR, enables 5-way mid batch)
  u16* KVG2 = nullptr;
  {
    size_t used = (size_t)(p - (char*)d_ws);
    size_t need = (size_t)NG*512*2 + 4096;
    if(ws_size >= used + need) KVG2 = (u16*)carve((size_t)NG*512*2);
  }

  float* QGio = (float*)d_out;                     // fp32 [NG,256]
  float* QDio = (float*)d_out + (size_t)NG*256;    // fp32 [ND,256]

  // ---- prep (batched) ----
  {
    T6 a;
    const int wi[6] = {2,13,6,17,10,21};
    u16* wo[6] = {WTinG, WTinD, WTqG, WTqD, WTaG, WTaD};
    const int kk[6] = {128,128,256,256,256,256};
    for(int i=0;i<6;i++){ a.W[i]=IN_F32(wi[i]); a.O[i]=wo[i]; a.K[i]=kk[i]; }
    transpose6<<<dim3(256,6), 256, 0, stream>>>(a);
  }
  {
    F6 a; Fb6 b;
    const int wk[6] = {4,8,15,19,4,8};
    const int bk[6] = {5,9,16,20,5,9};
    const int am[6] = {24,25,27,28,30,31};
    for(int i=0;i<6;i++){
      a.Wk[i]=IN_F32(wk[i]); a.A[i]=IN_F32(am[i]);
      a.O[i] = KVW[i>>1] + (size_t)(i & 1)*256*256;     // K rows 0-255, V rows 256-511
      b.bk[i]=IN_F32(bk[i]); b.A[i]=IN_F32(am[i]);
      b.O[i] = FBV[i>>1] + (i & 1)*256;
    }
    foldw6<<<dim3(256,6), 256, 0, stream>>>(a);
    foldb6<<<6, 256, 0, stream>>>(b);
  }
  // ---- CSR (batched) ----
  CSR3 c;
  c.src[0]=IN_I32(34); c.dst[0]=IN_I32(35); c.n[0]=ND;
  c.src[1]=IN_I32(36); c.dst[1]=IN_I32(37); c.n[1]=NG;
  c.src[2]=IN_I32(38); c.dst[2]=IN_I32(39); c.n[2]=NG;
  c.cnt[0]=cnt0; c.cnt[1]=cnt1; c.cnt[2]=cnt2;
  c.cur[0]=cur0; c.cur[1]=cur1; c.cur[2]=cur2;
  c.rs[0]=rs0; c.rs[1]=rs1; c.rs[2]=rs2;
  c.col[0]=col0; c.col[1]=col1; c.col[2]=col2;
  c.tot[0]=tot; c.tot[1]=tot+1; c.tot[2]=tot+2;
  const int eb = (E + 255) / 256;
  const int nb = (NG + 255) / 256;
  zero_k<<<(zn + 255) / 256, 256, 0, stream>>>(zone, zn);
  count3<<<dim3(eb,3), 256, 0, stream>>>(c, E);
  alloc3<<<dim3(nb,3), 256, 0, stream>>>(c);
  fill3<<<dim3(eb,3), 256, 0, stream>>>(c, E);

  const int yg = (NG + 63)/64, yd = (ND + 63)/64;

  // ---- input projections (batched: XG + XD) ----
  {
    GM5 pj{};
    pj.g[0].A = d_in[0]; pj.g[0].BT = WTinG; pj.g[0].bias = IN_F32(3);  pj.g[0].C = XG;
    pj.g[0].M = NG; pj.g[0].K = 128; pj.g[0].lda = 128; pj.g[0].ldc = 256;
    pj.g[0].lgy = 1; pj.g[0].base = 0; pj.g[0].epi = 0;
    pj.g[1].A = d_in[1]; pj.g[1].BT = WTinD; pj.g[1].bias = IN_F32(14); pj.g[1].C = XD;
    pj.g[1].M = ND; pj.g[1].K = 128; pj.g[1].lda = 128; pj.g[1].ldc = 256;
    pj.g[1].lgy = 1; pj.g[1].base = yg*2; pj.g[1].epi = 0;
    pj.n = 2; pj.nblk = yg*2 + yd*2;
    gemm_multi<1><<<pj.nblk, 256, 0, stream>>>(pj);
  }

  // ---- mid GEMMs (batched: QD + KV_g2d + QG + KV_d2g [+ KV_g2g]) ----
  {
    GM5 md{};
    md.g[0].A = XD; md.g[0].BT = WTqD;   md.g[0].bias = IN_F32(18); md.g[0].C = QDio;
    md.g[0].M = ND; md.g[0].K = 256; md.g[0].lda = 256; md.g[0].ldc = 256;
    md.g[0].lgy = 1; md.g[0].base = 0; md.g[0].epi = 1;
    int b1 = yd*2;
    md.g[1].A = XG; md.g[1].BT = KVW[0]; md.g[1].bias = FBV[0]; md.g[1].C = KVG;
    md.g[1].M = NG; md.g[1].K = 256; md.g[1].lda = 256; md.g[1].ldc = 512;
    md.g[1].lgy = 2; md.g[1].base = b1; md.g[1].epi = 0;
    int b2 = b1 + yg*4;
    md.g[2].A = XG; md.g[2].BT = WTqG;   md.g[2].bias = IN_F32(7); md.g[2].C = QGio;
    md.g[2].M = NG; md.g[2].K = 256; md.g[2].lda = 256; md.g[2].ldc = 256;
    md.g[2].lgy = 1; md.g[2].base = b2; md.g[2].epi = 1;
    int b3 = b2 + yg*2;
    md.g[3].A = XD; md.g[3].BT = KVW[1]; md.g[3].bias = FBV[1]; md.g[3].C = KVD;
    md.g[3].M = ND; md.g[3].K = 256; md.g[3].lda = 256; md.g[3].ldc = 512;
    md.g[3].lgy = 2; md.g[3].base = b3; md.g[3].epi = 0;
    int b4 = b3 + yd*4;
    if(KVG2){
      md.g[4].A = XG; md.g[4].BT = KVW[2]; md.g[4].bias = FBV[2]; md.g[4].C = KVG2;
      md.g[4].M = NG; md.g[4].K = 256; md.g[4].lda = 256; md.g[4].ldc = 512;
      md.g[4].lgy = 2; md.g[4].base = b4; md.g[4].epi = 0;
      md.n = 5; md.nblk = b4 + yg*4;
    } else {
      md.n = 4; md.nblk = b4;
    }
    gemm_multi<0><<<md.nblk, 256, 0, stream>>>(md);
  }

  // relation g2d message (needs QD + KV_g2d)
  message_gelu_k<1><<<(ND + 3) / 4, 256, 0, stream>>>(
      KVG, IN_F32(26), rs0, cnt0, col0,
      nullptr, nullptr, nullptr, nullptr, nullptr,
      QDio, ND);

  // KV_g2g fallback path (no KVG2): reuse KVG after msg1 consumed it
  if(!KVG2){
    GM5 k2{};
    k2.g[0].A = XG; k2.g[0].BT = KVW[2]; k2.g[0].bias = FBV[2]; k2.g[0].C = KVG;
    k2.g[0].M = NG; k2.g[0].K = 256; k2.g[0].lda = 256; k2.g[0].ldc = 512;
    k2.g[0].lgy = 2; k2.g[0].base = 0; k2.g[0].epi = 0;
    k2.n = 1; k2.nblk = yg*4;
    gemm_multi<0><<<k2.nblk, 256, 0, stream>>>(k2);
  }

  // relations d2g + g2g message (dst=g)
  message_gelu_k<2><<<(NG + 3) / 4, 256, 0, stream>>>(
      KVD, IN_F32(29), rs1, cnt1, col1,
      KVG2 ? KVG2 : KVG, IN_F32(32), rs2, cnt2, col2,
      QGio, NG);

  // ---- final epilogue GEMMs (batched, in place over d_out) ----
  {
    GE2 ep{};
    ep.g[0].A = (const u16*)QGio; ep.g[0].BT = WTaG; ep.g[0].bias = IN_F32(11);
    ep.g[0].C = QGio; ep.g[0].X = XG; ep.g[0].skip = IN_F32(12); ep.g[0].prelu = IN_F32(33);
    ep.g[0].M = NG; ep.g[0].base = 0;
    ep.g[1].A = (const u16*)QDio; ep.g[1].BT = WTaD; ep.g[1].bias = IN_F32(22);
    ep.g[1].C = QDio; ep.g[1].X = XD; ep.g[1].skip = IN_F32(23); ep.g[1].prelu = IN_F32(33);
    ep.g[1].M = ND; ep.g[1].base = (NG + 63)/64;
    ep.nblk = (NG + 63)/64 + (ND + 63)/64;
    gemm_epi2<<<ep.nblk, 256, 0, stream>>>(ep);
  }
  #undef IN_F32
  #undef IN_I32
}